// Round 8
// baseline (605.778 us; speedup 1.0000x reference)
//
#include <hip/hip_runtime.h>

// ---------------------------------------------------------------------------
// MusicGenerationV2: two zero-state LSTM cells, fully fused MFMA pipeline.
//   time:  gates = x @ W_ih_t^T + b ; to = sig(o)*tanh(sig(i)*tanh(g))
//   note:  gates = note_in @ W_ih_n^T + b ; y = (sig(o)*tanh(sig(i)*tanh(g)) > 0.5)
// fp16 split-precision (hi+lo, 3 products) = fp32-level accuracy.
// Round 8: TRANSPOSED time-MFMA -> zero-transpose pipeline.
//  - time MFMA computes gates^T = Wsel . x^T  (A=weights, B=x^T): lane = batch
//    row; k0 packs W rows so each lane's 48 output slots = 16 complete
//    (i,g,o) triples for h = kg*16 + m. Activations are fully lane-local.
//  - note MFMA k-slot map chosen as h = kg*16 + kc*8 + j (k0 packs wnF the
//    same way) -> note A-frag kc is the lane's OWN to[kc*8..kc*8+7].
//    NO tos LDS tile, NO cross-lane moves at all.
//  - bias enters via the k=24 pad channel (x pad lane = 1.0, W row = bias).
//  - LDS = wns double-buffer only (40 KB) -> 4 blocks/CU, 16 waves/CU.
// ---------------------------------------------------------------------------

typedef _Float16 half8  __attribute__((ext_vector_type(8)));
typedef float    f32x4  __attribute__((ext_vector_type(4)));

#define T_STEPS 128
#define NBROWS  12288      // 12 notes * 1024 batch
#define ROWS_WG 128        // rows per workgroup (4 waves x 32 rows)
#define NRT     96         // NBROWS / ROWS_WG
#define NCOLS   80         // note gate cols kept: i(24) g(24) o(24) pad(8)
#define WN_T_HALF 10240    // per-t frag-ordered wn halves (5nt*2kc*2p*512)

__device__ inline f32x4 mfma16(half8 a, half8 b, f32x4 c) {
  return __builtin_amdgcn_mfma_f32_16x16x32_f16(a, b, c, 0, 0, 0);
}

__device__ inline void gload_lds16(const _Float16* gsrc, _Float16* ldst) {
  __builtin_amdgcn_global_load_lds(
      (const __attribute__((address_space(1))) void*)gsrc,
      (__attribute__((address_space(3))) void*)ldst, 16, 0, 0);
}

#define SCALE_SIG  -1.4426950408889634f   // -log2(e)
#define SCALE_TANH  2.8853900817779268f   // 2*log2(e)

// ---------------------------------------------------------------------------
// Kernel 0: pack weights for the transposed pipeline.
// wselT[(ct*16+q)*32 + k], ct 0..11, q 0..15: A-row q of time-MFMA ct.
//   kgo=q>>2, r=q&3, s=ct*4+r, m=s/3, gidx=s%3 (i,g,o), h=kgo*16+m.
//   W row: i->h, g->128+h, o->192+h; scale: g->2log2e, i/o->-log2e.
//   k<24: W_ih_t; k==24: bias (b_ih_t+b_hh_t)*scale; k>24: 0.  hi/lo split.
// wnF[t*10240 + nt*2048 + kc*1024 + p*512 + l*8 + j]:
//   l=kg*16+cl; B[kslot=(kg,j)][col=cl] of note kc-MFMA =
//   Wn_sel[gatecol=nt*16+cl][h=kg*16+kc*8+j];
//   gatecol<24 -> W_ih_n row gatecol; 24<=gatecol<72 -> row gatecol+24
//   (skips dead f-gate rows 24..47); >=72 -> 0.  hi at p=0, lo at p=1.
// ---------------------------------------------------------------------------
__global__ __launch_bounds__(256) void k0_prep(
    const float* __restrict__ W_ih_t, const float* __restrict__ b_ih_t,
    const float* __restrict__ b_hh_t, const float* __restrict__ W_ih_n,
    _Float16* __restrict__ wselT_hi, _Float16* __restrict__ wselT_lo,
    _Float16* __restrict__ wnF)
{
  int id = blockIdx.x * 256 + threadIdx.x;
  if (id < 192 * 32) {
    int slot = id >> 5, k = id & 31;
    int ct = slot >> 4, q = slot & 15;
    int kgo = q >> 2, r = q & 3;
    int s = ct * 4 + r;
    int m = s / 3, gidx = s - 3 * m;
    int h = kgo * 16 + m;
    int wrow = (gidx == 0 ? 0 : (gidx == 1 ? 128 : 192)) + h;
    float scale = (gidx == 1) ? SCALE_TANH : SCALE_SIG;
    float v = 0.0f;
    if (k < 24)       v = W_ih_t[wrow * 24 + k] * scale;
    else if (k == 24) v = (b_ih_t[wrow] + b_hh_t[wrow]) * scale;
    _Float16 hi = (_Float16)v;
    wselT_hi[id] = hi;
    wselT_lo[id] = (_Float16)(v - (float)hi);
  }
  for (int e = id; e < T_STEPS * 5120; e += gridDim.x * 256) {
    int t = e / 5120, u = e - t * 5120;
    int nt = u >> 10, u2 = u & 1023;
    int kc = u2 >> 9, u3 = u2 & 511;
    int l = u3 >> 3, j = u3 & 7;
    int cl = l & 15, kg = l >> 4;
    int gcol = nt * 16 + cl;
    int h = kg * 16 + kc * 8 + j;          // the k-slot <-> h map
    float v = 0.0f;
    if (gcol < 72) {
      int wr = (gcol < 24) ? gcol : gcol + 24;
      v = W_ih_n[(size_t)wr * 8192 + t * 64 + h];
    }
    _Float16 hi = (_Float16)v;
    size_t base = (size_t)t * WN_T_HALF + nt * 2048 + kc * 1024 + u3;
    wnF[base]       = hi;
    wnF[base + 512] = (_Float16)(v - (float)hi);
  }
}

// ---------------------------------------------------------------------------
// Kernel 1: fused time-LSTM + note-GEMM partial sums. LDS = wns dbuf only.
// grid = NRT * tsplit blocks of 256 threads (4 waves, 32 rows each).
// ---------------------------------------------------------------------------
__global__ __launch_bounds__(256, 4)
void k1_time_note(
    const float* __restrict__ x,
    const _Float16* __restrict__ wselT_hi, const _Float16* __restrict__ wselT_lo,
    const _Float16* __restrict__ wnF,
    float* __restrict__ partials, int tchunk)
{
  __shared__ _Float16 wns[2][WN_T_HALF];   // 40960 B total -> 4 blocks/CU

  const int tid = threadIdx.x;
  const int l   = tid & 63;
  const int w   = tid >> 6;
  const int cl  = l & 15;
  const int kg  = l >> 4;

  const int rt   = blockIdx.x % NRT;
  const int ts   = blockIdx.x / NRT;
  const int row0 = rt * ROWS_WG;
  const int t0   = ts * tchunk;

  // time weights, A-frag resident: lane (cl,kg) holds A[row=cl][k=kg*8+j]
  half8 wth[12], wtl[12];
#pragma unroll
  for (int ct = 0; ct < 12; ++ct) {
    int off = (ct * 16 + cl) * 32 + kg * 8;
    wth[ct] = *(const half8*)(wselT_hi + off);
    wtl[ct] = *(const half8*)(wselT_lo + off);
  }

  f32x4 nacc[2][5];
#pragma unroll
  for (int mt = 0; mt < 2; ++mt)
#pragma unroll
    for (int nt = 0; nt < 5; ++nt)
      nacc[mt][nt] = (f32x4){0.f, 0.f, 0.f, 0.f};

  // x B-frag: lane (cl,kg) holds x[row0+w*32+mt*16+cl][k=kg*8+j]; kg=3 = pad
  const size_t xrow[2] = {
    (size_t)(row0 + w * 32 + 0  + cl) * 24 + kg * 8,
    (size_t)(row0 + w * 32 + 16 + cl) * 24 + kg * 8 };
  const bool xok = (kg < 3);

  float xcur[2][8];
#pragma unroll
  for (int mt = 0; mt < 2; ++mt) {
    f32x4 a = {0,0,0,0}, b = {0,0,0,0};
    if (xok) {
      const float* g = x + (size_t)t0 * NBROWS * 24 + xrow[mt];
      a = *(const f32x4*)g;
      b = *(const f32x4*)(g + 4);
    }
#pragma unroll
    for (int q = 0; q < 4; ++q) { xcur[mt][q] = a[q]; xcur[mt][4 + q] = b[q]; }
    if (!xok) xcur[mt][0] = 1.0f;          // k=24 bias channel
  }
  {
    const _Float16* src = wnF + (size_t)t0 * WN_T_HALF + w * 512 + l * 8;
    _Float16* dst = &wns[0][w * 512];
#pragma unroll
    for (int i = 0; i < 5; ++i)
      gload_lds16(src + i * 2048, dst + i * 2048);
  }
  __syncthreads();

  for (int tt = 0; tt < tchunk; ++tt) {
    const int rb = tt & 1, wb = rb ^ 1;
    int tg = t0 + tt + 1; if (tg > T_STEPS - 1) tg = T_STEPS - 1;

    // ---- 1. issue x[t+1] (HBM; covered by whole iteration) ----
    float xnxt[2][8];
#pragma unroll
    for (int mt = 0; mt < 2; ++mt) {
      f32x4 a = {0,0,0,0}, b = {0,0,0,0};
      if (xok) {
        const float* gp = x + (size_t)tg * NBROWS * 24 + xrow[mt];
        a = *(const f32x4*)gp;
        b = *(const f32x4*)(gp + 4);
      }
#pragma unroll
      for (int q = 0; q < 4; ++q) { xnxt[mt][q] = a[q]; xnxt[mt][4 + q] = b[q]; }
      if (!xok) xnxt[mt][0] = 1.0f;
    }

    // ---- 2. issue wn[t+1] -> wns[wb] ----
    {
      const _Float16* src = wnF + (size_t)tg * WN_T_HALF + w * 512 + l * 8;
      _Float16* dst = &wns[wb][w * 512];
#pragma unroll
      for (int i = 0; i < 5; ++i)
        gload_lds16(src + i * 2048, dst + i * 2048);
    }

    // ---- 3. per batch-tile: time MFMA -> lane-local activations -> A-frags
    half8 tah[2][2], tal[2][2];   // [mt][kc], kc slice = own m=kc*8..kc*8+7
#pragma unroll
    for (int mt = 0; mt < 2; ++mt) {
      half8 xh, xl;
#pragma unroll
      for (int q = 0; q < 8; ++q) {
        _Float16 h = (_Float16)xcur[mt][q];
        xh[q] = h;
        xl[q] = (_Float16)(xcur[mt][q] - (float)h);
      }
      f32x4 g[12];
#pragma unroll
      for (int ct = 0; ct < 12; ++ct) {
        f32x4 a = (f32x4){0.f, 0.f, 0.f, 0.f};
        a = mfma16(wth[ct], xh, a);    // hi*hi (bias rides k=24)
        a = mfma16(wth[ct], xl, a);    // hi_w * lo_x
        a = mfma16(wtl[ct], xh, a);    // lo_w * hi_x
        g[ct] = a;
      }
      // activations: lane holds gates for batch row cl, h = kg*16 + m
#pragma unroll
      for (int m = 0; m < 16; ++m) {
        const int si = 3 * m, sg = 3 * m + 1, so = 3 * m + 2;
        float zi = g[si >> 2][si & 3];
        float zg = g[sg >> 2][sg & 3];
        float zo = g[so >> 2][so & 3];
        float Ei = __builtin_amdgcn_exp2f(zi);            // e^{-i}
        float Eg = __builtin_amdgcn_exp2f(zg);            // e^{2g}
        float Eo = __builtin_amdgcn_exp2f(zo);            // e^{-o}
        float d1 = (1.0f + Ei) * (1.0f + Eg);
        float cp = (SCALE_TANH * Eg - SCALE_TANH) * __builtin_amdgcn_rcpf(d1);
        float Ec = __builtin_amdgcn_exp2f(cp);            // e^{2c}
        float d2 = (1.0f + Eo) * (1.0f + Ec);
        float to = (Ec - 1.0f) * __builtin_amdgcn_rcpf(d2);
        _Float16 th = (_Float16)to;
        _Float16 tl = (_Float16)(to - (float)th);
        if (m < 8) { tah[mt][0][m]     = th; tal[mt][0][m]     = tl; }
        else       { tah[mt][1][m - 8] = th; tal[mt][1][m - 8] = tl; }
      }
    }

    // ---- 4. note MFMA: nacc += to-frags x wns B-frags ----
    __builtin_amdgcn_s_setprio(1);
#pragma unroll
    for (int nt = 0; nt < 5; ++nt) {
#pragma unroll
      for (int kc = 0; kc < 2; ++kc) {
        const _Float16* bb = &wns[rb][nt * 2048 + kc * 1024 + l * 8];
        half8 bh = *(const half8*)(bb);
        half8 bl = *(const half8*)(bb + 512);
#pragma unroll
        for (int mt = 0; mt < 2; ++mt) {
          nacc[mt][nt] = mfma16(tah[mt][kc], bh, nacc[mt][nt]);
          nacc[mt][nt] = mfma16(tah[mt][kc], bl, nacc[mt][nt]);
          nacc[mt][nt] = mfma16(tal[mt][kc], bh, nacc[mt][nt]);
        }
      }
    }
    __builtin_amdgcn_s_setprio(0);

    // ---- 5. barrier: drains wn[t+1] + x[t+1]; swap buffers ----
    __syncthreads();
#pragma unroll
    for (int mt = 0; mt < 2; ++mt)
#pragma unroll
      for (int q = 0; q < 8; ++q) xcur[mt][q] = xnxt[mt][q];
  }

  // ---- write partial note-gate sums (C: row=batch kg*4+r, col=gate cl) ----
  float* pbase = partials + (size_t)ts * NBROWS * NCOLS;
#pragma unroll
  for (int mt = 0; mt < 2; ++mt)
#pragma unroll
    for (int nt = 0; nt < 5; ++nt)
#pragma unroll
      for (int r = 0; r < 4; ++r) {
        int row = row0 + w * 32 + mt * 16 + kg * 4 + r;
        int col = nt * 16 + cl;
        pbase[(size_t)row * NCOLS + col] = nacc[mt][nt][r];
      }
}

// ---------------------------------------------------------------------------
// Kernel 2: reduce tsplit partials, note activations, threshold.
// ---------------------------------------------------------------------------
__global__ __launch_bounds__(256) void k2_note_out(
    const float* __restrict__ partials,
    const float* __restrict__ b_ih_n, const float* __restrict__ b_hh_n,
    float* __restrict__ out, int tsplit)
{
  int idx = blockIdx.x * 256 + threadIdx.x;
  if (idx >= NBROWS * 24) return;
  int row = idx / 24, jj = idx - row * 24;
  float gi = 0.f, gg = 0.f, go = 0.f;
  for (int p = 0; p < tsplit; ++p) {
    const float* pp = partials + ((size_t)p * NBROWS + row) * NCOLS;
    gi += pp[jj];
    gg += pp[24 + jj];
    go += pp[48 + jj];
  }
  gi += b_ih_n[jj]      + b_hh_n[jj];
  gg += b_ih_n[48 + jj] + b_hh_n[48 + jj];
  go += b_ih_n[72 + jj] + b_hh_n[72 + jj];
  float si = 1.f / (1.f + expf(-gi));
  float so = 1.f / (1.f + expf(-go));
  float v = so * tanhf(si * tanhf(gg));
  out[idx] = (v > 0.5f) ? 1.0f : 0.0f;
}

// ---------------------------------------------------------------------------
extern "C" void kernel_launch(void* const* d_in, const int* in_sizes, int n_in,
                              void* d_out, int out_size, void* d_ws, size_t ws_size,
                              hipStream_t stream)
{
  (void)in_sizes; (void)n_in; (void)out_size;
  const float* x      = (const float*)d_in[0];
  const float* W_ih_t = (const float*)d_in[1];
  const float* b_ih_t = (const float*)d_in[3];
  const float* b_hh_t = (const float*)d_in[4];
  const float* W_ih_n = (const float*)d_in[5];
  const float* b_ih_n = (const float*)d_in[7];
  const float* b_hh_n = (const float*)d_in[8];
  float* out = (float*)d_out;

  char* ws = (char*)d_ws;
  _Float16* wselT_hi = (_Float16*)(ws + 0);                  // 12288 B
  _Float16* wselT_lo = (_Float16*)(ws + 12288);              // 12288 B
  _Float16* wnF      = (_Float16*)(ws + 32768);              // 2621440 B
  float*    partials = (float*)   (ws + 4194304);            // tsplit*12288*80*4

  int tsplit = 16;
  while (tsplit > 1 &&
         4194304ull + (size_t)tsplit * NBROWS * NCOLS * 4 > ws_size)
    tsplit >>= 1;
  int tchunk = T_STEPS / tsplit;

  k0_prep<<<dim3(512), dim3(256), 0, stream>>>(
      W_ih_t, b_ih_t, b_hh_t, W_ih_n, wselT_hi, wselT_lo, wnF);

  k1_time_note<<<dim3(NRT * tsplit), dim3(256), 0, stream>>>(
      x, wselT_hi, wselT_lo, wnF, partials, tchunk);

  k2_note_out<<<dim3((NBROWS * 24 + 255) / 256), dim3(256), 0, stream>>>(
      partials, b_ih_n, b_hh_n, out, tsplit);
}

// Round 9
// 164.753 us; speedup vs baseline: 3.6769x; 3.6769x over previous
//
#include <hip/hip_runtime.h>

// ---------------------------------------------------------------------------
// MusicGenerationV2: two zero-state LSTM cells, fully fused MFMA pipeline.
//   time:  gates = x @ W_ih_t^T + b ; to = sig(o)*tanh(sig(i)*tanh(g))
//   note:  gates = note_in @ W_ih_n^T + b ; y = (sig(o)*tanh(sig(i)*tanh(g)) > 0.5)
// fp16 split-precision (hi+lo, 3 products) = fp32-level accuracy.
// Round 9: pressure-proof, barrier-free k1.
//  - transposed time-MFMA + lane-local activations (round 8, verified).
//  - time weights in LDS (24.6 KB), ds_read per ct -> frees 96 VGPRs; the
//    allocator's 128-reg target now FITS (rounds 4-8: it spills/remats any
//    overage through scratch at ~GB scale).
//  - note B-frags read direct from global (wnF 2.6MB, L2/L3-hot) -> no wns
//    LDS, ZERO main-loop barriers; kc-interleaved so only one kc's to-frags
//    are live at a time.
//  - geometry: 192-thread blocks (3 waves, 96 rows), grid 1024 = exactly
//    4 blocks/CU on 256 CUs -> single generation, 3 waves/SIMD to saturate
//    the trans pipe (true floor: ~61 us of v_exp/v_rcp issue).
// ---------------------------------------------------------------------------

typedef _Float16 half8  __attribute__((ext_vector_type(8)));
typedef float    f32x4  __attribute__((ext_vector_type(4)));

#define T_STEPS 128
#define NBROWS  12288      // 12 notes * 1024 batch
#define ROWS_WG 96         // rows per workgroup (3 waves x 32 rows)
#define NRT     128        // NBROWS / ROWS_WG
#define NCOLS   80         // note gate cols kept: i(24) g(24) o(24) pad(8)
#define WN_T_HALF 10240    // per-t frag-ordered wn halves (5nt*2kc*2p*512)

__device__ inline f32x4 mfma16(half8 a, half8 b, f32x4 c) {
  return __builtin_amdgcn_mfma_f32_16x16x32_f16(a, b, c, 0, 0, 0);
}

__device__ inline void gload_lds16(const _Float16* gsrc, _Float16* ldst) {
  __builtin_amdgcn_global_load_lds(
      (const __attribute__((address_space(1))) void*)gsrc,
      (__attribute__((address_space(3))) void*)ldst, 16, 0, 0);
}

#define SCALE_SIG  -1.4426950408889634f   // -log2(e)
#define SCALE_TANH  2.8853900817779268f   // 2*log2(e)

// ---------------------------------------------------------------------------
// Kernel 0 (unchanged from round 8, verified): pack weights.
// wselT_hi/lo contiguous at ws+0 / ws+12288 (k1 stages both as one 24KB blob).
// wselT[(ct*16+q)*32 + k]: kgo=q>>2, r=q&3, s=ct*4+r, m=s/3, gidx=s%3,
//   h=kgo*16+m; W row i->h, g->128+h, o->192+h; g scaled 2log2e, i/o -log2e;
//   k<24 = W_ih_t, k==24 = (b_ih_t+b_hh_t)*scale, else 0.
// wnF[t*10240 + nt*2048 + kc*1024 + p*512 + l*8 + j]:
//   B[kslot=(kg,j)][col=cl] = Wn_sel[gatecol=nt*16+cl][h=kg*16+kc*8+j].
// ---------------------------------------------------------------------------
__global__ __launch_bounds__(256) void k0_prep(
    const float* __restrict__ W_ih_t, const float* __restrict__ b_ih_t,
    const float* __restrict__ b_hh_t, const float* __restrict__ W_ih_n,
    _Float16* __restrict__ wselT_hi, _Float16* __restrict__ wselT_lo,
    _Float16* __restrict__ wnF)
{
  int id = blockIdx.x * 256 + threadIdx.x;
  if (id < 192 * 32) {
    int slot = id >> 5, k = id & 31;
    int ct = slot >> 4, q = slot & 15;
    int kgo = q >> 2, r = q & 3;
    int s = ct * 4 + r;
    int m = s / 3, gidx = s - 3 * m;
    int h = kgo * 16 + m;
    int wrow = (gidx == 0 ? 0 : (gidx == 1 ? 128 : 192)) + h;
    float scale = (gidx == 1) ? SCALE_TANH : SCALE_SIG;
    float v = 0.0f;
    if (k < 24)       v = W_ih_t[wrow * 24 + k] * scale;
    else if (k == 24) v = (b_ih_t[wrow] + b_hh_t[wrow]) * scale;
    _Float16 hi = (_Float16)v;
    wselT_hi[id] = hi;
    wselT_lo[id] = (_Float16)(v - (float)hi);
  }
  for (int e = id; e < T_STEPS * 5120; e += gridDim.x * 256) {
    int t = e / 5120, u = e - t * 5120;
    int nt = u >> 10, u2 = u & 1023;
    int kc = u2 >> 9, u3 = u2 & 511;
    int l = u3 >> 3, j = u3 & 7;
    int cl = l & 15, kg = l >> 4;
    int gcol = nt * 16 + cl;
    int h = kg * 16 + kc * 8 + j;
    float v = 0.0f;
    if (gcol < 72) {
      int wr = (gcol < 24) ? gcol : gcol + 24;
      v = W_ih_n[(size_t)wr * 8192 + t * 64 + h];
    }
    _Float16 hi = (_Float16)v;
    size_t base = (size_t)t * WN_T_HALF + nt * 2048 + kc * 1024 + u3;
    wnF[base]       = hi;
    wnF[base + 512] = (_Float16)(v - (float)hi);
  }
}

// ---------------------------------------------------------------------------
// Kernel 1: fused time-LSTM + note-GEMM partial sums.
// grid = NRT * tsplit blocks of 192 threads (3 waves, 32 rows each).
// LDS = wsl (time weights, both planes) only. NO main-loop barriers.
// ---------------------------------------------------------------------------
__global__ __launch_bounds__(192, 2)
void k1_time_note(
    const float* __restrict__ x,
    const _Float16* __restrict__ wselT,   // hi plane; lo at +6144 halves
    const _Float16* __restrict__ wnF,
    float* __restrict__ partials, int tchunk)
{
  __shared__ _Float16 wsl[12288];   // 24576 B: [plane 0/1][192 slots][32 k]

  const int tid = threadIdx.x;
  const int l   = tid & 63;
  const int w   = tid >> 6;     // wave 0..2, owns rows [w*32, w*32+32)
  const int cl  = l & 15;
  const int kg  = l >> 4;       // 0..3

  const int rt   = blockIdx.x % NRT;
  const int ts   = blockIdx.x / NRT;
  const int row0 = rt * ROWS_WG;
  const int t0   = ts * tchunk;

  // ---- stage wselT (both planes) -> LDS: 24 chunks of 1024B ----
#pragma unroll
  for (int i = 0; i < 8; ++i) {
    int c = i * 3 + w;                       // wave-uniform chunk id
    gload_lds16(wselT + c * 512 + l * 8, wsl + c * 512);
  }

  f32x4 nacc[2][5];
#pragma unroll
  for (int mt = 0; mt < 2; ++mt)
#pragma unroll
    for (int nt = 0; nt < 5; ++nt)
      nacc[mt][nt] = (f32x4){0.f, 0.f, 0.f, 0.f};

  // x B-frag: lane (cl,kg) holds x[row0+w*32+mt*16+cl][k=kg*8+j]; kg=3 = pad
  const size_t xrow[2] = {
    (size_t)(row0 + w * 32 + 0  + cl) * 24 + kg * 8,
    (size_t)(row0 + w * 32 + 16 + cl) * 24 + kg * 8 };
  const bool xok = (kg < 3);

  float xcur[2][8];
#pragma unroll
  for (int mt = 0; mt < 2; ++mt) {
    f32x4 a = {0,0,0,0}, b = {0,0,0,0};
    if (xok) {
      const float* g = x + (size_t)t0 * NBROWS * 24 + xrow[mt];
      a = *(const f32x4*)g;
      b = *(const f32x4*)(g + 4);
    }
#pragma unroll
    for (int q = 0; q < 4; ++q) { xcur[mt][q] = a[q]; xcur[mt][4 + q] = b[q]; }
    if (!xok) xcur[mt][0] = 1.0f;          // k=24 bias channel
  }
  __syncthreads();   // wsl staged (drains gload_lds via vmcnt)

  for (int tt = 0; tt < tchunk; ++tt) {
    const int t = t0 + tt;
    int tg = t + 1; if (tg > T_STEPS - 1) tg = T_STEPS - 1;
    const _Float16* wnbase = wnF + (size_t)t * WN_T_HALF + l * 8;

    // ---- split x[t] -> fp16 hi/lo B-frags (xcur dead after) ----
    half8 xh[2], xl[2];
#pragma unroll
    for (int mt = 0; mt < 2; ++mt)
#pragma unroll
      for (int q = 0; q < 8; ++q) {
        _Float16 h = (_Float16)xcur[mt][q];
        xh[mt][q] = h;
        xl[mt][q] = (_Float16)(xcur[mt][q] - (float)h);
      }

    half8 tah[2][2], tal[2][2];   // [mt][kc]; only one kc live at a time
    float xnxt[2][8];

#pragma unroll
    for (int kk = 0; kk < 4; ++kk) {
      // ---- time MFMA for ct = 3kk..3kk+2 (weights from LDS) ----
      f32x4 g[2][3];
#pragma unroll
      for (int c = 0; c < 3; ++c) {
        int woff = ((kk * 3 + c) * 16 + cl) * 32 + kg * 8;
        half8 wh = *(half8*)&wsl[woff];
        half8 wl2 = *(half8*)&wsl[6144 + woff];
#pragma unroll
        for (int mt = 0; mt < 2; ++mt) {
          f32x4 a = (f32x4){0.f, 0.f, 0.f, 0.f};
          a = mfma16(wh,  xh[mt], a);   // hi*hi (bias rides k=24)
          a = mfma16(wh,  xl[mt], a);   // hi_w * lo_x
          a = mfma16(wl2, xh[mt], a);   // lo_w * hi_x
          g[mt][c] = a;
        }
      }
      // ---- activations m = 4kk..4kk+3 (lane-local) ----
#pragma unroll
      for (int mt = 0; mt < 2; ++mt)
#pragma unroll
        for (int mq = 0; mq < 4; ++mq) {
          const int ls = 3 * mq;
          float zi = g[mt][(ls)     >> 2][(ls)     & 3];
          float zg = g[mt][(ls + 1) >> 2][(ls + 1) & 3];
          float zo = g[mt][(ls + 2) >> 2][(ls + 2) & 3];
          float Ei = __builtin_amdgcn_exp2f(zi);            // e^{-i}
          float Eg = __builtin_amdgcn_exp2f(zg);            // e^{2g}
          float Eo = __builtin_amdgcn_exp2f(zo);            // e^{-o}
          float d1 = (1.0f + Ei) * (1.0f + Eg);
          float cp = (SCALE_TANH * Eg - SCALE_TANH) * __builtin_amdgcn_rcpf(d1);
          float Ec = __builtin_amdgcn_exp2f(cp);            // e^{2c}
          float d2 = (1.0f + Eo) * (1.0f + Ec);
          float to = (Ec - 1.0f) * __builtin_amdgcn_rcpf(d2);
          _Float16 th = (_Float16)to;
          _Float16 tl = (_Float16)(to - (float)th);
          const int m = kk * 4 + mq;
          tah[mt][m >> 3][m & 7] = th;
          tal[mt][m >> 3][m & 7] = tl;
        }

      // ---- after kk=1: note MFMA kc=0, then issue x[t+1] ----
      if (kk == 1) {
        half8 bh[5], bl[5];
#pragma unroll
        for (int nt = 0; nt < 5; ++nt) {
          bh[nt] = *(const half8*)(wnbase + nt * 2048);
          bl[nt] = *(const half8*)(wnbase + nt * 2048 + 512);
        }
        __builtin_amdgcn_s_setprio(1);
#pragma unroll
        for (int nt = 0; nt < 5; ++nt)
#pragma unroll
          for (int mt = 0; mt < 2; ++mt) {
            nacc[mt][nt] = mfma16(tah[mt][0], bh[nt], nacc[mt][nt]);
            nacc[mt][nt] = mfma16(tah[mt][0], bl[nt], nacc[mt][nt]);
            nacc[mt][nt] = mfma16(tal[mt][0], bh[nt], nacc[mt][nt]);
          }
        __builtin_amdgcn_s_setprio(0);
        // x[t+1]: covered by kk=2,3 + note kc=1 (~2000 cyc)
#pragma unroll
        for (int mt = 0; mt < 2; ++mt) {
          f32x4 a = {0,0,0,0}, b = {0,0,0,0};
          if (xok) {
            const float* gp = x + (size_t)tg * NBROWS * 24 + xrow[mt];
            a = *(const f32x4*)gp;
            b = *(const f32x4*)(gp + 4);
          }
#pragma unroll
          for (int q = 0; q < 4; ++q) { xnxt[mt][q] = a[q]; xnxt[mt][4+q] = b[q]; }
          if (!xok) xnxt[mt][0] = 1.0f;
        }
      }
    }

    // ---- note MFMA kc=1 ----
    {
      half8 bh[5], bl[5];
#pragma unroll
      for (int nt = 0; nt < 5; ++nt) {
        bh[nt] = *(const half8*)(wnbase + nt * 2048 + 1024);
        bl[nt] = *(const half8*)(wnbase + nt * 2048 + 1024 + 512);
      }
      __builtin_amdgcn_s_setprio(1);
#pragma unroll
      for (int nt = 0; nt < 5; ++nt)
#pragma unroll
        for (int mt = 0; mt < 2; ++mt) {
          nacc[mt][nt] = mfma16(tah[mt][1], bh[nt], nacc[mt][nt]);
          nacc[mt][nt] = mfma16(tah[mt][1], bl[nt], nacc[mt][nt]);
          nacc[mt][nt] = mfma16(tal[mt][1], bh[nt], nacc[mt][nt]);
        }
      __builtin_amdgcn_s_setprio(0);
    }

    // ---- rotate x prefetch ----
#pragma unroll
    for (int mt = 0; mt < 2; ++mt)
#pragma unroll
      for (int q = 0; q < 8; ++q) xcur[mt][q] = xnxt[mt][q];
  }

  // ---- write partial note-gate sums (C: row=batch kg*4+r, col=gate cl) ----
  float* pbase = partials + (size_t)ts * NBROWS * NCOLS;
#pragma unroll
  for (int mt = 0; mt < 2; ++mt)
#pragma unroll
    for (int nt = 0; nt < 5; ++nt)
#pragma unroll
      for (int r = 0; r < 4; ++r) {
        int row = row0 + w * 32 + mt * 16 + kg * 4 + r;
        int col = nt * 16 + cl;
        pbase[(size_t)row * NCOLS + col] = nacc[mt][nt][r];
      }
}

// ---------------------------------------------------------------------------
// Kernel 2: reduce tsplit partials, note activations, threshold.
// ---------------------------------------------------------------------------
__global__ __launch_bounds__(256) void k2_note_out(
    const float* __restrict__ partials,
    const float* __restrict__ b_ih_n, const float* __restrict__ b_hh_n,
    float* __restrict__ out, int tsplit)
{
  int idx = blockIdx.x * 256 + threadIdx.x;
  if (idx >= NBROWS * 24) return;
  int row = idx / 24, jj = idx - row * 24;
  float gi = 0.f, gg = 0.f, go = 0.f;
  for (int p = 0; p < tsplit; ++p) {
    const float* pp = partials + ((size_t)p * NBROWS + row) * NCOLS;
    gi += pp[jj];
    gg += pp[24 + jj];
    go += pp[48 + jj];
  }
  gi += b_ih_n[jj]      + b_hh_n[jj];
  gg += b_ih_n[48 + jj] + b_hh_n[48 + jj];
  go += b_ih_n[72 + jj] + b_hh_n[72 + jj];
  float si = 1.f / (1.f + expf(-gi));
  float so = 1.f / (1.f + expf(-go));
  float v = so * tanhf(si * tanhf(gg));
  out[idx] = (v > 0.5f) ? 1.0f : 0.0f;
}

// ---------------------------------------------------------------------------
extern "C" void kernel_launch(void* const* d_in, const int* in_sizes, int n_in,
                              void* d_out, int out_size, void* d_ws, size_t ws_size,
                              hipStream_t stream)
{
  (void)in_sizes; (void)n_in; (void)out_size;
  const float* x      = (const float*)d_in[0];
  const float* W_ih_t = (const float*)d_in[1];
  const float* b_ih_t = (const float*)d_in[3];
  const float* b_hh_t = (const float*)d_in[4];
  const float* W_ih_n = (const float*)d_in[5];
  const float* b_ih_n = (const float*)d_in[7];
  const float* b_hh_n = (const float*)d_in[8];
  float* out = (float*)d_out;

  char* ws = (char*)d_ws;
  _Float16* wselT_hi = (_Float16*)(ws + 0);                  // 12288 B
  _Float16* wselT_lo = (_Float16*)(ws + 12288);              // 12288 B (contig)
  _Float16* wnF      = (_Float16*)(ws + 32768);              // 2621440 B
  float*    partials = (float*)   (ws + 4194304);            // tsplit*12288*80*4

  // tsplit=8 -> grid 1024 blocks = exactly 4 blocks/CU, single generation.
  int tsplit = 8;
  while (tsplit > 1 &&
         4194304ull + (size_t)tsplit * NBROWS * NCOLS * 4 > ws_size)
    tsplit >>= 1;
  int tchunk = T_STEPS / tsplit;

  k0_prep<<<dim3(512), dim3(256), 0, stream>>>(
      W_ih_t, b_ih_t, b_hh_t, W_ih_n, wselT_hi, wselT_lo, wnF);

  k1_time_note<<<dim3(NRT * tsplit), dim3(192), 0, stream>>>(
      x, wselT_hi, wnF, partials, tchunk);

  k2_note_out<<<dim3((NBROWS * 24 + 255) / 256), dim3(256), 0, stream>>>(
      partials, b_ih_n, b_hh_n, out, tsplit);
}

// Round 10
// 141.103 us; speedup vs baseline: 4.2932x; 1.1676x over previous
//
#include <hip/hip_runtime.h>

// ---------------------------------------------------------------------------
// MusicGenerationV2: two zero-state LSTM cells, fully fused MFMA pipeline.
//   time:  gates = x @ W_ih_t^T + b ; to = sig(o)*tanh(sig(i)*tanh(g))
//   note:  gates = note_in @ W_ih_n^T + b ; y = (sig(o)*tanh(sig(i)*tanh(g)) > 0.5)
// fp16 split-precision (hi+lo, 3 products) = fp32-level accuracy.
// Round 10: ILP-complete pipelining on the round-9 structure (verified).
//  - wn kc0 B-frags loaded at t-step TOP (covered by time-MFMA kk=0,1);
//    kc1 loaded right after kc0's note-MFMA (covered by kk=2,3). No load
//    waits with <400cyc of cover anywhere in the loop.
//  - x prefetch ping-pong (xA/xB) + 2x unroll: rotate movs gone.
//  - 256-thread blocks (4 waves, 128 rows), NRT=96, tsplit=16 -> grid 1536 =
//    exactly 3 residency generations at 2 blocks/CU; 8 waves/CU.
//  - LDS = time weights only (24.6 KB); zero main-loop barriers.
// ---------------------------------------------------------------------------

typedef _Float16 half8  __attribute__((ext_vector_type(8)));
typedef float    f32x4  __attribute__((ext_vector_type(4)));

#define T_STEPS 128
#define NBROWS  12288      // 12 notes * 1024 batch
#define ROWS_WG 128        // rows per workgroup (4 waves x 32 rows)
#define NRT     96         // NBROWS / ROWS_WG
#define NCOLS   80         // note gate cols kept: i(24) g(24) o(24) pad(8)
#define WN_T_HALF 10240    // per-t frag-ordered wn halves (5nt*2kc*2p*512)

__device__ inline f32x4 mfma16(half8 a, half8 b, f32x4 c) {
  return __builtin_amdgcn_mfma_f32_16x16x32_f16(a, b, c, 0, 0, 0);
}

__device__ inline void gload_lds16(const _Float16* gsrc, _Float16* ldst) {
  __builtin_amdgcn_global_load_lds(
      (const __attribute__((address_space(1))) void*)gsrc,
      (__attribute__((address_space(3))) void*)ldst, 16, 0, 0);
}

#define SCALE_SIG  -1.4426950408889634f   // -log2(e)
#define SCALE_TANH  2.8853900817779268f   // 2*log2(e)

// ---------------------------------------------------------------------------
// Kernel 0 (unchanged, verified): pack weights.
// wselT[(ct*16+q)*32 + k]: kgo=q>>2, r=q&3, s=ct*4+r, m=s/3, gidx=s%3,
//   h=kgo*16+m; W row i->h, g->128+h, o->192+h; g scaled 2log2e, i/o -log2e;
//   k<24 = W_ih_t, k==24 = (b_ih_t+b_hh_t)*scale, else 0. hi plane then lo.
// wnF[t*10240 + nt*2048 + kc*1024 + p*512 + l*8 + j]:
//   B[kslot=(kg,j)][col=cl] = Wn_sel[gatecol=nt*16+cl][h=kg*16+kc*8+j].
// ---------------------------------------------------------------------------
__global__ __launch_bounds__(256) void k0_prep(
    const float* __restrict__ W_ih_t, const float* __restrict__ b_ih_t,
    const float* __restrict__ b_hh_t, const float* __restrict__ W_ih_n,
    _Float16* __restrict__ wselT_hi, _Float16* __restrict__ wselT_lo,
    _Float16* __restrict__ wnF)
{
  int id = blockIdx.x * 256 + threadIdx.x;
  if (id < 192 * 32) {
    int slot = id >> 5, k = id & 31;
    int ct = slot >> 4, q = slot & 15;
    int kgo = q >> 2, r = q & 3;
    int s = ct * 4 + r;
    int m = s / 3, gidx = s - 3 * m;
    int h = kgo * 16 + m;
    int wrow = (gidx == 0 ? 0 : (gidx == 1 ? 128 : 192)) + h;
    float scale = (gidx == 1) ? SCALE_TANH : SCALE_SIG;
    float v = 0.0f;
    if (k < 24)       v = W_ih_t[wrow * 24 + k] * scale;
    else if (k == 24) v = (b_ih_t[wrow] + b_hh_t[wrow]) * scale;
    _Float16 hi = (_Float16)v;
    wselT_hi[id] = hi;
    wselT_lo[id] = (_Float16)(v - (float)hi);
  }
  for (int e = id; e < T_STEPS * 5120; e += gridDim.x * 256) {
    int t = e / 5120, u = e - t * 5120;
    int nt = u >> 10, u2 = u & 1023;
    int kc = u2 >> 9, u3 = u2 & 511;
    int l = u3 >> 3, j = u3 & 7;
    int cl = l & 15, kg = l >> 4;
    int gcol = nt * 16 + cl;
    int h = kg * 16 + kc * 8 + j;
    float v = 0.0f;
    if (gcol < 72) {
      int wr = (gcol < 24) ? gcol : gcol + 24;
      v = W_ih_n[(size_t)wr * 8192 + t * 64 + h];
    }
    _Float16 hi = (_Float16)v;
    size_t base = (size_t)t * WN_T_HALF + nt * 2048 + kc * 1024 + u3;
    wnF[base]       = hi;
    wnF[base + 512] = (_Float16)(v - (float)hi);
  }
}

// ---------------------------------------------------------------------------
// One fused t-step: time MFMA + activations + note MFMA, fully pipelined.
// Reads x[t] from xc regs; prefetches x[tg] into xn regs mid-step.
// ---------------------------------------------------------------------------
__device__ __forceinline__ void t_step(
    int t, int tg, float (*xc)[8], float (*xn)[8],
    const float* __restrict__ x, const _Float16* __restrict__ wnF,
    const _Float16* wsl, const size_t* xrow, bool xok,
    int cl, int kg, int l, f32x4 (*nacc)[5])
{
  const _Float16* wn_t = wnF + (size_t)t * WN_T_HALF + l * 8;

  // ---- issue wn kc0 loads (consumed after kk=1: ~500cyc cover) ----
  half8 b0h[5], b0l[5];
#pragma unroll
  for (int nt = 0; nt < 5; ++nt) {
    b0h[nt] = *(const half8*)(wn_t + nt * 2048);
    b0l[nt] = *(const half8*)(wn_t + nt * 2048 + 512);
  }

  // ---- split x[t] -> fp16 hi/lo B-frags ----
  half8 xh[2], xl[2];
#pragma unroll
  for (int mt = 0; mt < 2; ++mt)
#pragma unroll
    for (int q = 0; q < 8; ++q) {
      _Float16 h = (_Float16)xc[mt][q];
      xh[mt][q] = h;
      xl[mt][q] = (_Float16)(xc[mt][q] - (float)h);
    }

  half8 ta0h[2], ta0l[2], ta1h[2], ta1l[2];
  half8 b1h[5], b1l[5];

#pragma unroll
  for (int kk = 0; kk < 4; ++kk) {
    // ---- time MFMA for ct = 3kk..3kk+2 (weights from LDS) ----
    f32x4 g[2][3];
#pragma unroll
    for (int c = 0; c < 3; ++c) {
      int woff = ((kk * 3 + c) * 16 + cl) * 32 + kg * 8;
      half8 wh  = *(const half8*)&wsl[woff];
      half8 wl2 = *(const half8*)&wsl[6144 + woff];
#pragma unroll
      for (int mt = 0; mt < 2; ++mt) {
        f32x4 a = (f32x4){0.f, 0.f, 0.f, 0.f};
        a = mfma16(wh,  xh[mt], a);   // hi*hi (bias rides k=24)
        a = mfma16(wh,  xl[mt], a);   // hi_w * lo_x
        a = mfma16(wl2, xh[mt], a);   // lo_w * hi_x
        g[mt][c] = a;
      }
    }
    // ---- lane-local activations, m = 4kk..4kk+3 ----
#pragma unroll
    for (int mt = 0; mt < 2; ++mt)
#pragma unroll
      for (int mq = 0; mq < 4; ++mq) {
        const int ls = 3 * mq;
        float zi = g[mt][(ls)     >> 2][(ls)     & 3];
        float zg = g[mt][(ls + 1) >> 2][(ls + 1) & 3];
        float zo = g[mt][(ls + 2) >> 2][(ls + 2) & 3];
        float Ei = __builtin_amdgcn_exp2f(zi);            // e^{-i}
        float Eg = __builtin_amdgcn_exp2f(zg);            // e^{2g}
        float Eo = __builtin_amdgcn_exp2f(zo);            // e^{-o}
        float d1 = (1.0f + Ei) * (1.0f + Eg);
        float cp = (SCALE_TANH * Eg - SCALE_TANH) * __builtin_amdgcn_rcpf(d1);
        float Ec = __builtin_amdgcn_exp2f(cp);            // e^{2c}
        float d2 = (1.0f + Eo) * (1.0f + Ec);
        float to = (Ec - 1.0f) * __builtin_amdgcn_rcpf(d2);
        _Float16 th = (_Float16)to;
        _Float16 tl = (_Float16)(to - (float)th);
        const int m = kk * 4 + mq;
        if (kk < 2) { ta0h[mt][m]     = th; ta0l[mt][m]     = tl; }
        else        { ta1h[mt][m - 8] = th; ta1l[mt][m - 8] = tl; }
      }

    if (kk == 1) {
      // ---- note MFMA kc0 (b0 loads have ~500cyc cover by now) ----
      __builtin_amdgcn_s_setprio(1);
#pragma unroll
      for (int nt = 0; nt < 5; ++nt)
#pragma unroll
        for (int mt = 0; mt < 2; ++mt) {
          nacc[mt][nt] = mfma16(ta0h[mt], b0h[nt], nacc[mt][nt]);
          nacc[mt][nt] = mfma16(ta0h[mt], b0l[nt], nacc[mt][nt]);
          nacc[mt][nt] = mfma16(ta0l[mt], b0h[nt], nacc[mt][nt]);
        }
      __builtin_amdgcn_s_setprio(0);
      // ---- issue wn kc1 loads (covered by kk=2,3) ----
#pragma unroll
      for (int nt = 0; nt < 5; ++nt) {
        b1h[nt] = *(const half8*)(wn_t + nt * 2048 + 1024);
        b1l[nt] = *(const half8*)(wn_t + nt * 2048 + 1536);
      }
      // ---- issue x[tg] prefetch (covered by kk=2,3 + kc1 + next top) ----
#pragma unroll
      for (int mt = 0; mt < 2; ++mt) {
        f32x4 a = {0, 0, 0, 0}, b = {0, 0, 0, 0};
        if (xok) {
          const float* gp = x + (size_t)tg * NBROWS * 24 + xrow[mt];
          a = *(const f32x4*)gp;
          b = *(const f32x4*)(gp + 4);
        }
#pragma unroll
        for (int q = 0; q < 4; ++q) { xn[mt][q] = a[q]; xn[mt][4 + q] = b[q]; }
        if (!xok) xn[mt][0] = 1.0f;   // k=24 bias channel
      }
    }
  }

  // ---- note MFMA kc1 ----
  __builtin_amdgcn_s_setprio(1);
#pragma unroll
  for (int nt = 0; nt < 5; ++nt)
#pragma unroll
    for (int mt = 0; mt < 2; ++mt) {
      nacc[mt][nt] = mfma16(ta1h[mt], b1h[nt], nacc[mt][nt]);
      nacc[mt][nt] = mfma16(ta1h[mt], b1l[nt], nacc[mt][nt]);
      nacc[mt][nt] = mfma16(ta1l[mt], b1h[nt], nacc[mt][nt]);
    }
  __builtin_amdgcn_s_setprio(0);
}

// ---------------------------------------------------------------------------
// Kernel 1: fused time-LSTM + note-GEMM partial sums.
// grid = NRT * tsplit blocks of 256 threads (4 waves, 32 rows each).
// LDS = time weights only. ZERO main-loop barriers.
// ---------------------------------------------------------------------------
__global__ __launch_bounds__(256, 2)
void k1_time_note(
    const float* __restrict__ x,
    const _Float16* __restrict__ wselT,   // hi plane; lo at +6144 halves
    const _Float16* __restrict__ wnF,
    float* __restrict__ partials, int tchunk)
{
  __shared__ _Float16 wsl[12288];   // 24576 B: [plane][192 slots][32 k]

  const int tid = threadIdx.x;
  const int l   = tid & 63;
  const int w   = tid >> 6;     // wave 0..3, owns rows [w*32, w*32+32)
  const int cl  = l & 15;
  const int kg  = l >> 4;       // 0..3

  const int rt   = blockIdx.x % NRT;
  const int ts   = blockIdx.x / NRT;
  const int row0 = rt * ROWS_WG;
  const int t0   = ts * tchunk;

  // ---- stage wselT (both planes, 24 KB) -> LDS: 6 chunks of 1KB per wave ----
#pragma unroll
  for (int i = 0; i < 6; ++i) {
    int c = i * 4 + w;                       // wave-uniform chunk id
    gload_lds16(wselT + c * 512 + l * 8, wsl + c * 512);
  }

  f32x4 nacc[2][5];
#pragma unroll
  for (int mt = 0; mt < 2; ++mt)
#pragma unroll
    for (int nt = 0; nt < 5; ++nt)
      nacc[mt][nt] = (f32x4){0.f, 0.f, 0.f, 0.f};

  // x B-frag: lane (cl,kg) holds x[row0+w*32+mt*16+cl][k=kg*8+j]; kg=3 = pad
  const size_t xrow[2] = {
    (size_t)(row0 + w * 32 + 0  + cl) * 24 + kg * 8,
    (size_t)(row0 + w * 32 + 16 + cl) * 24 + kg * 8 };
  const bool xok = (kg < 3);

  float xA[2][8], xB[2][8];
#pragma unroll
  for (int mt = 0; mt < 2; ++mt) {
    f32x4 a = {0, 0, 0, 0}, b = {0, 0, 0, 0};
    if (xok) {
      const float* g = x + (size_t)t0 * NBROWS * 24 + xrow[mt];
      a = *(const f32x4*)g;
      b = *(const f32x4*)(g + 4);
    }
#pragma unroll
    for (int q = 0; q < 4; ++q) { xA[mt][q] = a[q]; xA[mt][4 + q] = b[q]; }
    if (!xok) xA[mt][0] = 1.0f;
  }
  __syncthreads();   // wsl staged (drains gload_lds)

  // ---- main loop, unrolled x2 with ping-pong x prefetch (no rotate) ----
  for (int tt = 0; tt < tchunk; tt += 2) {
    int ta = t0 + tt, tb = ta + 1;
    int tg2 = (tt + 2 < tchunk) ? (tb + 1) : tb;   // clamp inside chunk
    t_step(ta, tb,  xA, xB, x, wnF, wsl, xrow, xok, cl, kg, l, nacc);
    t_step(tb, tg2, xB, xA, x, wnF, wsl, xrow, xok, cl, kg, l, nacc);
  }

  // ---- write partial note-gate sums (C: row=batch kg*4+r, col=gate cl) ----
  float* pbase = partials + (size_t)ts * NBROWS * NCOLS;
#pragma unroll
  for (int mt = 0; mt < 2; ++mt)
#pragma unroll
    for (int nt = 0; nt < 5; ++nt)
#pragma unroll
      for (int r = 0; r < 4; ++r) {
        int row = row0 + w * 32 + mt * 16 + kg * 4 + r;
        int col = nt * 16 + cl;
        pbase[(size_t)row * NCOLS + col] = nacc[mt][nt][r];
      }
}

// ---------------------------------------------------------------------------
// Kernel 2: reduce tsplit partials, note activations, threshold.
// ---------------------------------------------------------------------------
__global__ __launch_bounds__(256) void k2_note_out(
    const float* __restrict__ partials,
    const float* __restrict__ b_ih_n, const float* __restrict__ b_hh_n,
    float* __restrict__ out, int tsplit)
{
  int idx = blockIdx.x * 256 + threadIdx.x;
  if (idx >= NBROWS * 24) return;
  int row = idx / 24, jj = idx - row * 24;
  float gi = 0.f, gg = 0.f, go = 0.f;
  for (int p = 0; p < tsplit; ++p) {
    const float* pp = partials + ((size_t)p * NBROWS + row) * NCOLS;
    gi += pp[jj];
    gg += pp[24 + jj];
    go += pp[48 + jj];
  }
  gi += b_ih_n[jj]      + b_hh_n[jj];
  gg += b_ih_n[48 + jj] + b_hh_n[48 + jj];
  go += b_ih_n[72 + jj] + b_hh_n[72 + jj];
  float si = 1.f / (1.f + expf(-gi));
  float so = 1.f / (1.f + expf(-go));
  float v = so * tanhf(si * tanhf(gg));
  out[idx] = (v > 0.5f) ? 1.0f : 0.0f;
}

// ---------------------------------------------------------------------------
extern "C" void kernel_launch(void* const* d_in, const int* in_sizes, int n_in,
                              void* d_out, int out_size, void* d_ws, size_t ws_size,
                              hipStream_t stream)
{
  (void)in_sizes; (void)n_in; (void)out_size;
  const float* x      = (const float*)d_in[0];
  const float* W_ih_t = (const float*)d_in[1];
  const float* b_ih_t = (const float*)d_in[3];
  const float* b_hh_t = (const float*)d_in[4];
  const float* W_ih_n = (const float*)d_in[5];
  const float* b_ih_n = (const float*)d_in[7];
  const float* b_hh_n = (const float*)d_in[8];
  float* out = (float*)d_out;

  char* ws = (char*)d_ws;
  _Float16* wselT_hi = (_Float16*)(ws + 0);                  // 12288 B
  _Float16* wselT_lo = (_Float16*)(ws + 12288);              // 12288 B (contig)
  _Float16* wnF      = (_Float16*)(ws + 32768);              // 2621440 B
  float*    partials = (float*)   (ws + 4194304);            // tsplit*12288*80*4

  // tsplit=16 -> grid 1536 = exactly 3 generations at 2 blocks/CU.
  int tsplit = 16;
  while (tsplit > 1 &&
         4194304ull + (size_t)tsplit * NBROWS * NCOLS * 4 > ws_size)
    tsplit >>= 1;
  int tchunk = T_STEPS / tsplit;

  k0_prep<<<dim3(512), dim3(256), 0, stream>>>(
      W_ih_t, b_ih_t, b_hh_t, W_ih_n, wselT_hi, wselT_lo, wnF);

  k1_time_note<<<dim3(NRT * tsplit), dim3(256), 0, stream>>>(
      x, wselT_hi, wnF, partials, tchunk);

  k2_note_out<<<dim3((NBROWS * 24 + 255) / 256), dim3(256), 0, stream>>>(
      partials, b_ih_n, b_hh_n, out, tsplit);
}

// Round 11
// 138.737 us; speedup vs baseline: 4.3664x; 1.0171x over previous
//
#include <hip/hip_runtime.h>

// ---------------------------------------------------------------------------
// MusicGenerationV2: two zero-state LSTM cells, fully fused MFMA pipeline.
//   time:  gates = x @ W_ih_t^T + b ; to = sig(o)*tanh(sig(i)*tanh(g))
//   note:  gates = note_in @ W_ih_n^T + b ; y = (sig(o)*tanh(sig(i)*tanh(g)) > 0.5)
// fp16 split-precision (hi+lo, 3 products) = fp32-level accuracy.
// Round 11: register diet -> 3 waves/SIMD.
//  Round 10 was issue-starved at 2 waves/SIMD (occupancy 20%): reported 128
//  VGPR + ~64 accumulator regs = ~192/wave -> floor(512/192)=2. This round
//  processes the two batch-tiles (mt) SEQUENTIALLY inside each t-step:
//  xh/xl 16->8, g 24->12, b0/b1 never co-live -> peak ~168 total -> 3
//  blocks/CU. Same ops, same order per accumulator = bit-identical output.
//  Cost: wsl ds_reads x2 (LDS pipe is idle; ~290 cyc/t-step).
// ---------------------------------------------------------------------------

typedef _Float16 half8  __attribute__((ext_vector_type(8)));
typedef float    f32x4  __attribute__((ext_vector_type(4)));

#define T_STEPS 128
#define NBROWS  12288      // 12 notes * 1024 batch
#define ROWS_WG 128        // rows per workgroup (4 waves x 32 rows)
#define NRT     96         // NBROWS / ROWS_WG
#define NCOLS   80         // note gate cols kept: i(24) g(24) o(24) pad(8)
#define WN_T_HALF 10240    // per-t frag-ordered wn halves (5nt*2kc*2p*512)

__device__ inline f32x4 mfma16(half8 a, half8 b, f32x4 c) {
  return __builtin_amdgcn_mfma_f32_16x16x32_f16(a, b, c, 0, 0, 0);
}

__device__ inline void gload_lds16(const _Float16* gsrc, _Float16* ldst) {
  __builtin_amdgcn_global_load_lds(
      (const __attribute__((address_space(1))) void*)gsrc,
      (__attribute__((address_space(3))) void*)ldst, 16, 0, 0);
}

#define SCALE_SIG  -1.4426950408889634f   // -log2(e)
#define SCALE_TANH  2.8853900817779268f   // 2*log2(e)

// ---------------------------------------------------------------------------
// Kernel 0 (unchanged, verified): pack weights.
// wselT[(ct*16+q)*32 + k]: kgo=q>>2, r=q&3, s=ct*4+r, m=s/3, gidx=s%3,
//   h=kgo*16+m; W row i->h, g->128+h, o->192+h; g scaled 2log2e, i/o -log2e;
//   k<24 = W_ih_t, k==24 = (b_ih_t+b_hh_t)*scale, else 0. hi plane then lo.
// wnF[t*10240 + nt*2048 + kc*1024 + p*512 + l*8 + j]:
//   B[kslot=(kg,j)][col=cl] = Wn_sel[gatecol=nt*16+cl][h=kg*16+kc*8+j].
// ---------------------------------------------------------------------------
__global__ __launch_bounds__(256) void k0_prep(
    const float* __restrict__ W_ih_t, const float* __restrict__ b_ih_t,
    const float* __restrict__ b_hh_t, const float* __restrict__ W_ih_n,
    _Float16* __restrict__ wselT_hi, _Float16* __restrict__ wselT_lo,
    _Float16* __restrict__ wnF)
{
  int id = blockIdx.x * 256 + threadIdx.x;
  if (id < 192 * 32) {
    int slot = id >> 5, k = id & 31;
    int ct = slot >> 4, q = slot & 15;
    int kgo = q >> 2, r = q & 3;
    int s = ct * 4 + r;
    int m = s / 3, gidx = s - 3 * m;
    int h = kgo * 16 + m;
    int wrow = (gidx == 0 ? 0 : (gidx == 1 ? 128 : 192)) + h;
    float scale = (gidx == 1) ? SCALE_TANH : SCALE_SIG;
    float v = 0.0f;
    if (k < 24)       v = W_ih_t[wrow * 24 + k] * scale;
    else if (k == 24) v = (b_ih_t[wrow] + b_hh_t[wrow]) * scale;
    _Float16 hi = (_Float16)v;
    wselT_hi[id] = hi;
    wselT_lo[id] = (_Float16)(v - (float)hi);
  }
  for (int e = id; e < T_STEPS * 5120; e += gridDim.x * 256) {
    int t = e / 5120, u = e - t * 5120;
    int nt = u >> 10, u2 = u & 1023;
    int kc = u2 >> 9, u3 = u2 & 511;
    int l = u3 >> 3, j = u3 & 7;
    int cl = l & 15, kg = l >> 4;
    int gcol = nt * 16 + cl;
    int h = kg * 16 + kc * 8 + j;
    float v = 0.0f;
    if (gcol < 72) {
      int wr = (gcol < 24) ? gcol : gcol + 24;
      v = W_ih_n[(size_t)wr * 8192 + t * 64 + h];
    }
    _Float16 hi = (_Float16)v;
    size_t base = (size_t)t * WN_T_HALF + nt * 2048 + kc * 1024 + u3;
    wnF[base]       = hi;
    wnF[base + 512] = (_Float16)(v - (float)hi);
  }
}

// ---------------------------------------------------------------------------
// One fused t-step, mt-SEQUENTIAL for minimal live set.
// ---------------------------------------------------------------------------
__device__ __forceinline__ void t_step(
    int t, int tg, float (*xc)[8], float (*xn)[8],
    const float* __restrict__ x, const _Float16* __restrict__ wnF,
    const _Float16* wsl, const size_t* xrow, bool xok,
    int cl, int kg, int l, f32x4 (*nacc)[5])
{
  const _Float16* wn_t = wnF + (size_t)t * WN_T_HALF + l * 8;

  // ---- issue wn kc0 loads (consumed at mt=0's kk==1: ~400cyc cover) ----
  half8 b0h[5], b0l[5];
#pragma unroll
  for (int nt = 0; nt < 5; ++nt) {
    b0h[nt] = *(const half8*)(wn_t + nt * 2048);
    b0l[nt] = *(const half8*)(wn_t + nt * 2048 + 512);
  }

  half8 ta1h[2], ta1l[2];        // kc1 A-frags, held until step end
  half8 b1h[5], b1l[5];          // issued at mt=1 kk==1 (b0 dead there)

#pragma unroll
  for (int mt = 0; mt < 2; ++mt) {
    // ---- split x[t] for THIS mt only (8 regs) ----
    half8 xh, xl;
#pragma unroll
    for (int q = 0; q < 8; ++q) {
      _Float16 h = (_Float16)xc[mt][q];
      xh[q] = h;
      xl[q] = (_Float16)(xc[mt][q] - (float)h);
    }

    half8 ta0h, ta0l;            // kc0 A-frag, transient per mt
#pragma unroll
    for (int kk = 0; kk < 4; ++kk) {
      // ---- time MFMA for ct = 3kk..3kk+2 (weights from LDS) ----
      f32x4 g[3];
#pragma unroll
      for (int c = 0; c < 3; ++c) {
        int woff = ((kk * 3 + c) * 16 + cl) * 32 + kg * 8;
        half8 wh  = *(const half8*)&wsl[woff];
        half8 wl2 = *(const half8*)&wsl[6144 + woff];
        f32x4 a = (f32x4){0.f, 0.f, 0.f, 0.f};
        a = mfma16(wh,  xh, a);   // hi*hi (bias rides k=24)
        a = mfma16(wh,  xl, a);   // hi_w * lo_x
        a = mfma16(wl2, xh, a);   // lo_w * hi_x
        g[c] = a;
      }
      // ---- lane-local activations, m = 4kk..4kk+3 ----
#pragma unroll
      for (int mq = 0; mq < 4; ++mq) {
        const int ls = 3 * mq;
        float zi = g[(ls)     >> 2][(ls)     & 3];
        float zg = g[(ls + 1) >> 2][(ls + 1) & 3];
        float zo = g[(ls + 2) >> 2][(ls + 2) & 3];
        float Ei = __builtin_amdgcn_exp2f(zi);            // e^{-i}
        float Eg = __builtin_amdgcn_exp2f(zg);            // e^{2g}
        float Eo = __builtin_amdgcn_exp2f(zo);            // e^{-o}
        float d1 = (1.0f + Ei) * (1.0f + Eg);
        float cp = (SCALE_TANH * Eg - SCALE_TANH) * __builtin_amdgcn_rcpf(d1);
        float Ec = __builtin_amdgcn_exp2f(cp);            // e^{2c}
        float d2 = (1.0f + Eo) * (1.0f + Ec);
        float to = (Ec - 1.0f) * __builtin_amdgcn_rcpf(d2);
        _Float16 th = (_Float16)to;
        _Float16 tl = (_Float16)(to - (float)th);
        const int m = kk * 4 + mq;
        if (kk < 2) { ta0h[m]         = th; ta0l[m]         = tl; }
        else        { ta1h[mt][m - 8] = th; ta1l[mt][m - 8] = tl; }
      }

      if (kk == 1) {
        // ---- note MFMA kc0 for this mt (b0's last use at mt==1) ----
        __builtin_amdgcn_s_setprio(1);
#pragma unroll
        for (int nt = 0; nt < 5; ++nt) {
          nacc[mt][nt] = mfma16(ta0h, b0h[nt], nacc[mt][nt]);
          nacc[mt][nt] = mfma16(ta0h, b0l[nt], nacc[mt][nt]);
          nacc[mt][nt] = mfma16(ta0l, b0h[nt], nacc[mt][nt]);
        }
        __builtin_amdgcn_s_setprio(0);
        // ---- issue x[tg] prefetch for this mt ----
        {
          f32x4 a = {0, 0, 0, 0}, b = {0, 0, 0, 0};
          if (xok) {
            const float* gp = x + (size_t)tg * NBROWS * 24 + xrow[mt];
            a = *(const f32x4*)gp;
            b = *(const f32x4*)(gp + 4);
          }
#pragma unroll
          for (int q = 0; q < 4; ++q) { xn[mt][q] = a[q]; xn[mt][4 + q] = b[q]; }
          if (!xok) xn[mt][0] = 1.0f;   // k=24 bias channel
        }
        // ---- issue wn kc1 loads once b0 is dead (covered by kk=2,3) ----
        if (mt == 1) {
#pragma unroll
          for (int nt = 0; nt < 5; ++nt) {
            b1h[nt] = *(const half8*)(wn_t + nt * 2048 + 1024);
            b1l[nt] = *(const half8*)(wn_t + nt * 2048 + 1536);
          }
        }
      }
    }
  }

  // ---- note MFMA kc1, both mt ----
  __builtin_amdgcn_s_setprio(1);
#pragma unroll
  for (int nt = 0; nt < 5; ++nt)
#pragma unroll
    for (int mt = 0; mt < 2; ++mt) {
      nacc[mt][nt] = mfma16(ta1h[mt], b1h[nt], nacc[mt][nt]);
      nacc[mt][nt] = mfma16(ta1h[mt], b1l[nt], nacc[mt][nt]);
      nacc[mt][nt] = mfma16(ta1l[mt], b1h[nt], nacc[mt][nt]);
    }
  __builtin_amdgcn_s_setprio(0);
}

// ---------------------------------------------------------------------------
// Kernel 1: fused time-LSTM + note-GEMM partial sums.
// grid = NRT * tsplit blocks of 256 threads (4 waves, 32 rows each).
// LDS = time weights only (24.6 KB). ZERO main-loop barriers.
// ---------------------------------------------------------------------------
__global__ __launch_bounds__(256, 2)
void k1_time_note(
    const float* __restrict__ x,
    const _Float16* __restrict__ wselT,   // hi plane; lo at +6144 halves
    const _Float16* __restrict__ wnF,
    float* __restrict__ partials, int tchunk)
{
  __shared__ _Float16 wsl[12288];   // 24576 B: [plane][192 slots][32 k]

  const int tid = threadIdx.x;
  const int l   = tid & 63;
  const int w   = tid >> 6;     // wave 0..3, owns rows [w*32, w*32+32)
  const int cl  = l & 15;
  const int kg  = l >> 4;       // 0..3

  const int rt   = blockIdx.x % NRT;
  const int ts   = blockIdx.x / NRT;
  const int row0 = rt * ROWS_WG;
  const int t0   = ts * tchunk;

  // ---- stage wselT (both planes, 24 KB) -> LDS: 6 chunks of 1KB per wave ----
#pragma unroll
  for (int i = 0; i < 6; ++i) {
    int c = i * 4 + w;                       // wave-uniform chunk id
    gload_lds16(wselT + c * 512 + l * 8, wsl + c * 512);
  }

  f32x4 nacc[2][5];
#pragma unroll
  for (int mt = 0; mt < 2; ++mt)
#pragma unroll
    for (int nt = 0; nt < 5; ++nt)
      nacc[mt][nt] = (f32x4){0.f, 0.f, 0.f, 0.f};

  // x B-frag: lane (cl,kg) holds x[row0+w*32+mt*16+cl][k=kg*8+j]; kg=3 = pad
  const size_t xrow[2] = {
    (size_t)(row0 + w * 32 + 0  + cl) * 24 + kg * 8,
    (size_t)(row0 + w * 32 + 16 + cl) * 24 + kg * 8 };
  const bool xok = (kg < 3);

  float xA[2][8], xB[2][8];
#pragma unroll
  for (int mt = 0; mt < 2; ++mt) {
    f32x4 a = {0, 0, 0, 0}, b = {0, 0, 0, 0};
    if (xok) {
      const float* g = x + (size_t)t0 * NBROWS * 24 + xrow[mt];
      a = *(const f32x4*)g;
      b = *(const f32x4*)(g + 4);
    }
#pragma unroll
    for (int q = 0; q < 4; ++q) { xA[mt][q] = a[q]; xA[mt][4 + q] = b[q]; }
    if (!xok) xA[mt][0] = 1.0f;
  }
  __syncthreads();   // wsl staged (drains gload_lds)

  // ---- main loop, unrolled x2 with ping-pong x prefetch ----
  for (int tt = 0; tt < tchunk; tt += 2) {
    int ta = t0 + tt, tb = ta + 1;
    int tg2 = (tt + 2 < tchunk) ? (tb + 1) : tb;   // clamp inside chunk
    t_step(ta, tb,  xA, xB, x, wnF, wsl, xrow, xok, cl, kg, l, nacc);
    t_step(tb, tg2, xB, xA, x, wnF, wsl, xrow, xok, cl, kg, l, nacc);
  }

  // ---- write partial note-gate sums (C: row=batch kg*4+r, col=gate cl) ----
  float* pbase = partials + (size_t)ts * NBROWS * NCOLS;
#pragma unroll
  for (int mt = 0; mt < 2; ++mt)
#pragma unroll
    for (int nt = 0; nt < 5; ++nt)
#pragma unroll
      for (int r = 0; r < 4; ++r) {
        int row = row0 + w * 32 + mt * 16 + kg * 4 + r;
        int col = nt * 16 + cl;
        pbase[(size_t)row * NCOLS + col] = nacc[mt][nt][r];
      }
}

// ---------------------------------------------------------------------------
// Kernel 2: reduce tsplit partials, note activations, threshold.
// ---------------------------------------------------------------------------
__global__ __launch_bounds__(256) void k2_note_out(
    const float* __restrict__ partials,
    const float* __restrict__ b_ih_n, const float* __restrict__ b_hh_n,
    float* __restrict__ out, int tsplit)
{
  int idx = blockIdx.x * 256 + threadIdx.x;
  if (idx >= NBROWS * 24) return;
  int row = idx / 24, jj = idx - row * 24;
  float gi = 0.f, gg = 0.f, go = 0.f;
  for (int p = 0; p < tsplit; ++p) {
    const float* pp = partials + ((size_t)p * NBROWS + row) * NCOLS;
    gi += pp[jj];
    gg += pp[24 + jj];
    go += pp[48 + jj];
  }
  gi += b_ih_n[jj]      + b_hh_n[jj];
  gg += b_ih_n[48 + jj] + b_hh_n[48 + jj];
  go += b_ih_n[72 + jj] + b_hh_n[72 + jj];
  float si = 1.f / (1.f + expf(-gi));
  float so = 1.f / (1.f + expf(-go));
  float v = so * tanhf(si * tanhf(gg));
  out[idx] = (v > 0.5f) ? 1.0f : 0.0f;
}

// ---------------------------------------------------------------------------
extern "C" void kernel_launch(void* const* d_in, const int* in_sizes, int n_in,
                              void* d_out, int out_size, void* d_ws, size_t ws_size,
                              hipStream_t stream)
{
  (void)in_sizes; (void)n_in; (void)out_size;
  const float* x      = (const float*)d_in[0];
  const float* W_ih_t = (const float*)d_in[1];
  const float* b_ih_t = (const float*)d_in[3];
  const float* b_hh_t = (const float*)d_in[4];
  const float* W_ih_n = (const float*)d_in[5];
  const float* b_ih_n = (const float*)d_in[7];
  const float* b_hh_n = (const float*)d_in[8];
  float* out = (float*)d_out;

  char* ws = (char*)d_ws;
  _Float16* wselT_hi = (_Float16*)(ws + 0);                  // 12288 B
  _Float16* wselT_lo = (_Float16*)(ws + 12288);              // 12288 B (contig)
  _Float16* wnF      = (_Float16*)(ws + 32768);              // 2621440 B
  float*    partials = (float*)   (ws + 4194304);            // tsplit*12288*80*4

  // tsplit=16 -> grid 1536: 2 gens at 3 blk/CU, 3 gens at 2 blk/CU.
  int tsplit = 16;
  while (tsplit > 1 &&
         4194304ull + (size_t)tsplit * NBROWS * NCOLS * 4 > ws_size)
    tsplit >>= 1;
  int tchunk = T_STEPS / tsplit;

  k0_prep<<<dim3(512), dim3(256), 0, stream>>>(
      W_ih_t, b_ih_t, b_hh_t, W_ih_n, wselT_hi, wselT_lo, wnF);

  k1_time_note<<<dim3(NRT * tsplit), dim3(256), 0, stream>>>(
      x, wselT_hi, wnF, partials, tchunk);

  k2_note_out<<<dim3((NBROWS * 24 + 255) / 256), dim3(256), 0, stream>>>(
      partials, b_ih_n, b_hh_n, out, tsplit);
}